// Round 2
// baseline (436.653 us; speedup 1.0000x reference)
//
#include <hip/hip_runtime.h>
#include <math.h>

#define NPTS 4096
#define BATCH 4
#define KNB 16
#define BIG 3.0e38f

// ---------------------------------------------------------------------------
// Kernel 1: one block (256 thr = 4 waves) per (point i, batch b, dataset ds).
// Exact 16-NN (self excluded) + kappa. Writes kappa[row] and 16 neighbor idx.
// ---------------------------------------------------------------------------
__global__ __launch_bounds__(256)
void knn_kappa_kernel(const float* __restrict__ ori,
                      const float* __restrict__ adv,
                      const float* __restrict__ nrm,
                      float* __restrict__ kappaWs,
                      int* __restrict__ idxWs) {
  const int i    = blockIdx.x;
  const int b    = blockIdx.y;
  const int ds   = blockIdx.z;
  const int t    = threadIdx.x;
  const int lane = t & 63;
  const int w    = t >> 6;

  const float* __restrict__ P  = (ds == 0 ? ori : adv) + (size_t)b * 3 * NPTS;
  const float* __restrict__ Xp = P;
  const float* __restrict__ Yp = P + NPTS;
  const float* __restrict__ Zp = P + 2 * NPTS;

  __shared__ float wTopD[4][KNB];
  __shared__ int   wTopJ[4][KNB];

  const float xi = Xp[i], yi = Yp[i], zi = Zp[i];

  // Each thread owns columns j = u*256 + t, u in [0,16). All reg indices
  // are compile-time (unrolled) so nothing spills to scratch.
  float d[16];
  float lmin = BIG;
  int   larg = 0;
#pragma unroll
  for (int u = 0; u < 16; ++u) {
    const int j = u * 256 + t;
    const float dx = Xp[j] - xi;
    const float dy = Yp[j] - yi;
    const float dz = Zp[j] - zi;
    float d2 = fmaf(dx, dx, fmaf(dy, dy, dz * dz));
    if (j == i) d2 = BIG;          // exclude self (ref drops idx[...,0]=self)
    d[u] = d2;
    const bool c = d2 < lmin;
    lmin = c ? d2 : lmin;
    larg = c ? j : larg;
  }

  // Per-wave extraction of its local top-16 (over 1024 candidates). No
  // barriers: wave-autonomous. Running per-lane min; only the round winner
  // rescans its 16 registers.
  for (int r = 0; r < KNB; ++r) {
    float m = lmin;
    m = fminf(m, __shfl_xor(m, 32));
    m = fminf(m, __shfl_xor(m, 16));
    m = fminf(m, __shfl_xor(m, 8));
    m = fminf(m, __shfl_xor(m, 4));
    m = fminf(m, __shfl_xor(m, 2));
    m = fminf(m, __shfl_xor(m, 1));
    const unsigned long long ball = __ballot(lmin == m);
    const int wl = __ffsll(ball) - 1;
    const int wj = __shfl(larg, wl);
    if (lane == 0) { wTopD[w][r] = m; wTopJ[w][r] = wj; }
    if (lane == wl) {
      const int wu = wj >> 8;       // wj % 256 == t for the winner
#pragma unroll
      for (int u = 0; u < 16; ++u) d[u] = (u == wu) ? BIG : d[u];
      lmin = BIG; larg = 0;
#pragma unroll
      for (int u = 0; u < 16; ++u) {
        const bool c = d[u] < lmin;
        lmin = c ? d[u] : lmin;
        larg = c ? (u * 256 + t) : larg;
      }
    }
  }
  __syncthreads();

  // Wave 0 merges the 4x16 = 64 candidates (one per lane) into global top-16.
  if (t < 64) {
    float cd = wTopD[lane >> 4][lane & 15];
    int   cj = wTopJ[lane >> 4][lane & 15];
    int   nbj = 0;
#pragma unroll
    for (int r = 0; r < KNB; ++r) {
      float m = cd;
      m = fminf(m, __shfl_xor(m, 32));
      m = fminf(m, __shfl_xor(m, 16));
      m = fminf(m, __shfl_xor(m, 8));
      m = fminf(m, __shfl_xor(m, 4));
      m = fminf(m, __shfl_xor(m, 2));
      m = fminf(m, __shfl_xor(m, 1));
      const unsigned long long ball = __ballot(cd == m);
      const int wl = __ffsll(ball) - 1;
      const int wj = __shfl(cj, wl);
      if (lane == wl) cd = BIG;     // extract
      if (lane == r)  nbj = wj;     // lane r keeps the r-th nearest neighbor
    }

    if (lane < KNB) {
      // kappa contribution of this neighbor: |(v . n_i) / max(||v||,1e-12)|
      const float px = Xp[nbj], py = Yp[nbj], pz = Zp[nbj];
      const float vx = px - xi, vy = py - yi, vz = pz - zi;
      float L = sqrtf(fmaf(vx, vx, fmaf(vy, vy, vz * vz)));
      L = fmaxf(L, 1e-12f);
      const float* __restrict__ nb_ = nrm + (size_t)b * 3 * NPTS;
      const float nx = nb_[i], ny = nb_[NPTS + i], nz = nb_[2 * NPTS + i];
      float c = fabsf(fmaf(vx, nx, fmaf(vy, ny, vz * nz)) / L);
      // sum over lanes 0..15 (partners stay inside the active group)
      c += __shfl_xor(c, 1);
      c += __shfl_xor(c, 2);
      c += __shfl_xor(c, 4);
      c += __shfl_xor(c, 8);
      const size_t row = (size_t)(ds * BATCH + b) * NPTS + i;
      if (lane == 0) kappaWs[row] = c * (1.0f / 16.0f);
      idxWs[row * KNB + lane] = nbj;
    }
  }
}

// ---------------------------------------------------------------------------
// Kernel 2: per (b,i): gather 16 neighbor kappas for both datasets, std with
// ddof=1, d = std_ori - std_adv + 1e-6, block-reduce d^2 into partials.
// ---------------------------------------------------------------------------
__global__ __launch_bounds__(256)
void std_dist_kernel(const float* __restrict__ kappaWs,
                     const int* __restrict__ idxWs,
                     float* __restrict__ partial) {
  const int i = blockIdx.x * 256 + threadIdx.x;
  const int b = blockIdx.y;

  float s[2];
#pragma unroll
  for (int ds = 0; ds < 2; ++ds) {
    const size_t kb = (size_t)(ds * BATCH + b) * NPTS;
    const int* __restrict__ ip = idxWs + (kb + i) * KNB;
    float kv[16];
    float sum = 0.f;
#pragma unroll
    for (int u = 0; u < 16; ++u) {
      kv[u] = kappaWs[kb + ip[u]];
      sum += kv[u];
    }
    const float mean = sum * (1.0f / 16.0f);
    float ss = 0.f;
#pragma unroll
    for (int u = 0; u < 16; ++u) {
      const float dv = kv[u] - mean;
      ss = fmaf(dv, dv, ss);
    }
    s[ds] = sqrtf(ss * (1.0f / 15.0f));   // unbiased (ddof=1)
  }

  float dq = s[0] - s[1] + 1e-6f;          // PairwiseDistance eps inside norm
  dq = dq * dq;

  // block reduce 256 -> 1
  dq += __shfl_xor(dq, 32);
  dq += __shfl_xor(dq, 16);
  dq += __shfl_xor(dq, 8);
  dq += __shfl_xor(dq, 4);
  dq += __shfl_xor(dq, 2);
  dq += __shfl_xor(dq, 1);
  __shared__ float red[4];
  if ((threadIdx.x & 63) == 0) red[threadIdx.x >> 6] = dq;
  __syncthreads();
  if (threadIdx.x == 0)
    partial[b * 16 + blockIdx.x] = red[0] + red[1] + red[2] + red[3];
}

// ---------------------------------------------------------------------------
// Kernel 3: 64 partials (4 batches x 16 blocks) -> mean_b sqrt(sum_b)
// ---------------------------------------------------------------------------
__global__ void finalize_kernel(const float* __restrict__ partial,
                                float* __restrict__ out) {
  const int l = threadIdx.x;   // 64 threads
  float v = partial[l];
  // reduce within each group of 16 (one batch)
  v += __shfl_xor(v, 1);
  v += __shfl_xor(v, 2);
  v += __shfl_xor(v, 4);
  v += __shfl_xor(v, 8);
  float s = sqrtf(v);
  // sum the 4 distinct group values
  s += __shfl_xor(s, 16);
  s += __shfl_xor(s, 32);
  if (l == 0) out[0] = s * 0.25f;
}

extern "C" void kernel_launch(void* const* d_in, const int* in_sizes, int n_in,
                              void* d_out, int out_size, void* d_ws, size_t ws_size,
                              hipStream_t stream) {
  const float* ori = (const float*)d_in[0];
  const float* adv = (const float*)d_in[1];
  const float* nrm = (const float*)d_in[2];
  float* out = (float*)d_out;

  // workspace carve (~2.2 MB total)
  float* kappaWs = (float*)d_ws;                                  // 2*4*4096 f32
  int*   idxWs   = (int*)((char*)d_ws + (size_t)2 * BATCH * NPTS * 4);
  float* partial = (float*)((char*)d_ws + (size_t)2 * BATCH * NPTS * 4
                                        + (size_t)2 * BATCH * NPTS * KNB * 4);

  dim3 g1(NPTS, BATCH, 2);
  knn_kappa_kernel<<<g1, 256, 0, stream>>>(ori, adv, nrm, kappaWs, idxWs);

  dim3 g2(NPTS / 256, BATCH);
  std_dist_kernel<<<g2, 256, 0, stream>>>(kappaWs, idxWs, partial);

  finalize_kernel<<<dim3(1), 64, 0, stream>>>(partial, out);
}

// Round 3
// 180.395 us; speedup vs baseline: 2.4205x; 2.4205x over previous
//
#include <hip/hip_runtime.h>
#include <math.h>

#define NPTS 4096
#define BATCH 4
#define KNB 16
#define BIG 3.0e38f
#define CAP 1024   // LDS candidate capacity; exact unless >1008 of 4095 pts share one 1/4-exponent bin

// ---------------------------------------------------------------------------
// Bitonic sort of 64 (d,slot) pairs, one per lane, ascending in d.
// ---------------------------------------------------------------------------
__device__ __forceinline__ void bsort_stage(float& d, int& s, int lane, int k, int j) {
  const float od = __shfl_xor(d, j);
  const int   os = __shfl_xor(s, j);
  const bool keepMin = ((lane & k) == 0) == ((lane & j) == 0);
  const bool takeO = keepMin ? (od < d) : (od > d);
  d = takeO ? od : d;
  s = takeO ? os : s;
}

__device__ __forceinline__ void bitonic_sort64(float& d, int& s, int lane) {
#pragma unroll
  for (int k = 2; k <= 64; k <<= 1) {
#pragma unroll
    for (int j = k >> 1; j >= 1; j >>= 1)
      bsort_stage(d, s, lane, k, j);
  }
}

__device__ __forceinline__ void bitonic_merge64(float& d, int& s, int lane) {
#pragma unroll
  for (int j = 32; j >= 1; j >>= 1)
    bsort_stage(d, s, lane, 64, j);   // k=64: ascending everywhere
}

// ---------------------------------------------------------------------------
// Kernel 1: one block (256 thr) per (point i, batch b, dataset ds).
// Exact 16-NN via histogram radix-select + bitonic sort. Writes kappa + idx.
// ---------------------------------------------------------------------------
__global__ __launch_bounds__(256)
void knn_kappa_kernel(const float* __restrict__ ori,
                      const float* __restrict__ adv,
                      const float* __restrict__ nrm,
                      float* __restrict__ kappaWs,
                      int* __restrict__ idxWs) {
  const int i    = blockIdx.x;
  const int b    = blockIdx.y;
  const int ds   = blockIdx.z;
  const int t    = threadIdx.x;
  const int lane = t & 63;
  const int w    = t >> 6;

  const float* __restrict__ P  = (ds == 0 ? ori : adv) + (size_t)b * 3 * NPTS;
  const float* __restrict__ Xp = P;
  const float* __restrict__ Yp = P + NPTS;
  const float* __restrict__ Zp = P + 2 * NPTS;

  __shared__ unsigned int hist[1024];
  __shared__ float candD[CAP];
  __shared__ int   candI[CAP];
  __shared__ unsigned int cnt;
  __shared__ unsigned int selB;

#pragma unroll
  for (int u = 0; u < 4; ++u) hist[u * 256 + t] = 0;
  if (t == 0) cnt = 0;
  __syncthreads();

  const float xi = Xp[i], yi = Yp[i], zi = Zp[i];

  // Distance pass: 16 candidates per thread, kept in registers for the
  // collect pass. Histogram key = top 10 bits of f32(d2) (monotone, d2>=0).
  float d[16];
#pragma unroll
  for (int u = 0; u < 16; ++u) {
    const int j = u * 256 + t;
    const float dx = Xp[j] - xi;
    const float dy = Yp[j] - yi;
    const float dz = Zp[j] - zi;
    float d2 = fmaf(dx, dx, fmaf(dy, dy, dz * dz));
    if (j == i) d2 = BIG;          // exclude self (bin ~1019, never selected)
    d[u] = d2;
    atomicAdd(&hist[__float_as_uint(d2) >> 21], 1u);
  }
  __syncthreads();

  // Wave 0: first bin B with cumulative count >= KNB (exact threshold bin).
  if (w == 0) {
    unsigned h[16];
    unsigned seg = 0;
#pragma unroll
    for (int u = 0; u < 16; ++u) { h[u] = hist[lane * 16 + u]; seg += h[u]; }
    unsigned scan = seg;                       // inclusive scan across lanes
#pragma unroll
    for (int sft = 1; sft < 64; sft <<= 1) {
      const unsigned o = __shfl_up(scan, sft);
      if (lane >= sft) scan += o;
    }
    const unsigned excl = scan - seg;
    const unsigned long long ball = __ballot(scan >= KNB);
    const int l0 = __ffsll(ball) - 1;          // first lane reaching cum>=K
    if (lane == l0) {
      unsigned c = excl;
      int Bu = 0;
      bool found = false;
#pragma unroll
      for (int u = 0; u < 16; ++u) {
        c += h[u];
        if (!found && c >= KNB) { Bu = u; found = true; }
      }
      selB = (unsigned)(lane * 16 + Bu);
    }
  }
  __syncthreads();
  const unsigned B = selB;

  // Collect pass: all candidates with bin <= B (count M >= 16, typically small).
#pragma unroll
  for (int u = 0; u < 16; ++u) {
    if ((__float_as_uint(d[u]) >> 21) <= B) {
      const unsigned pos = atomicAdd(&cnt, 1u);
      if (pos < CAP) { candD[pos] = d[u]; candI[pos] = u * 256 + t; }
    }
  }
  __syncthreads();

  // Wave 0: exact top-16 of the M collected candidates via bitonic sort.
  if (w == 0) {
    const int M = (int)(cnt < CAP ? cnt : CAP);
    float sd = (lane < M) ? candD[lane] : BIG;
    int   si = (lane < M) ? lane : -1;
    bitonic_sort64(sd, si, lane);
    for (int c0 = 64; c0 < M; c0 += 64) {       // rare: M > 64
      const int slot = c0 + lane;
      float vd = (slot < M) ? candD[slot] : BIG;
      int   vi = (slot < M) ? slot : -1;
      bitonic_sort64(vd, vi, lane);
      const float rd = __shfl_xor(vd, 63);      // reverse -> descending
      const int   ri = __shfl_xor(vi, 63);
      if (rd < sd) { sd = rd; si = ri; }        // min-half of merge, bitonic
      bitonic_merge64(sd, si, lane);            // re-sort ascending
    }

    // lanes 0..15 now hold the 16 nearest (ascending). Kappa + idx out.
    if (lane < KNB) {
      const int nbj = candI[si];
      const float px = Xp[nbj], py = Yp[nbj], pz = Zp[nbj];
      const float vx = px - xi, vy = py - yi, vz = pz - zi;
      float L = sqrtf(fmaf(vx, vx, fmaf(vy, vy, vz * vz)));
      L = fmaxf(L, 1e-12f);
      const float* __restrict__ nb_ = nrm + (size_t)b * 3 * NPTS;
      const float nx = nb_[i], ny = nb_[NPTS + i], nz = nb_[2 * NPTS + i];
      float c = fabsf(fmaf(vx, nx, fmaf(vy, ny, vz * nz)) / L);
      c += __shfl_xor(c, 1);
      c += __shfl_xor(c, 2);
      c += __shfl_xor(c, 4);
      c += __shfl_xor(c, 8);
      const size_t row = (size_t)(ds * BATCH + b) * NPTS + i;
      if (lane == 0) kappaWs[row] = c * (1.0f / 16.0f);
      idxWs[row * KNB + lane] = nbj;
    }
  }
}

// ---------------------------------------------------------------------------
// Kernel 2: per (b,i): gather 16 neighbor kappas for both datasets, std with
// ddof=1, d = std_ori - std_adv + 1e-6, block-reduce d^2 into partials.
// ---------------------------------------------------------------------------
__global__ __launch_bounds__(256)
void std_dist_kernel(const float* __restrict__ kappaWs,
                     const int* __restrict__ idxWs,
                     float* __restrict__ partial) {
  const int i = blockIdx.x * 256 + threadIdx.x;
  const int b = blockIdx.y;

  float s[2];
#pragma unroll
  for (int ds = 0; ds < 2; ++ds) {
    const size_t kb = (size_t)(ds * BATCH + b) * NPTS;
    const int* __restrict__ ip = idxWs + (kb + i) * KNB;
    float kv[16];
    float sum = 0.f;
#pragma unroll
    for (int u = 0; u < 16; ++u) {
      kv[u] = kappaWs[kb + ip[u]];
      sum += kv[u];
    }
    const float mean = sum * (1.0f / 16.0f);
    float ss = 0.f;
#pragma unroll
    for (int u = 0; u < 16; ++u) {
      const float dv = kv[u] - mean;
      ss = fmaf(dv, dv, ss);
    }
    s[ds] = sqrtf(ss * (1.0f / 15.0f));   // unbiased (ddof=1)
  }

  float dq = s[0] - s[1] + 1e-6f;          // PairwiseDistance eps inside norm
  dq = dq * dq;

  dq += __shfl_xor(dq, 32);
  dq += __shfl_xor(dq, 16);
  dq += __shfl_xor(dq, 8);
  dq += __shfl_xor(dq, 4);
  dq += __shfl_xor(dq, 2);
  dq += __shfl_xor(dq, 1);
  __shared__ float red[4];
  if ((threadIdx.x & 63) == 0) red[threadIdx.x >> 6] = dq;
  __syncthreads();
  if (threadIdx.x == 0)
    partial[b * 16 + blockIdx.x] = red[0] + red[1] + red[2] + red[3];
}

// ---------------------------------------------------------------------------
// Kernel 3: 64 partials (4 batches x 16 blocks) -> mean_b sqrt(sum_b)
// ---------------------------------------------------------------------------
__global__ void finalize_kernel(const float* __restrict__ partial,
                                float* __restrict__ out) {
  const int l = threadIdx.x;   // 64 threads
  float v = partial[l];
  v += __shfl_xor(v, 1);
  v += __shfl_xor(v, 2);
  v += __shfl_xor(v, 4);
  v += __shfl_xor(v, 8);
  float s = sqrtf(v);
  s += __shfl_xor(s, 16);
  s += __shfl_xor(s, 32);
  if (l == 0) out[0] = s * 0.25f;
}

extern "C" void kernel_launch(void* const* d_in, const int* in_sizes, int n_in,
                              void* d_out, int out_size, void* d_ws, size_t ws_size,
                              hipStream_t stream) {
  const float* ori = (const float*)d_in[0];
  const float* adv = (const float*)d_in[1];
  const float* nrm = (const float*)d_in[2];
  float* out = (float*)d_out;

  float* kappaWs = (float*)d_ws;                                  // 2*4*4096 f32
  int*   idxWs   = (int*)((char*)d_ws + (size_t)2 * BATCH * NPTS * 4);
  float* partial = (float*)((char*)d_ws + (size_t)2 * BATCH * NPTS * 4
                                        + (size_t)2 * BATCH * NPTS * KNB * 4);

  dim3 g1(NPTS, BATCH, 2);
  knn_kappa_kernel<<<g1, 256, 0, stream>>>(ori, adv, nrm, kappaWs, idxWs);

  dim3 g2(NPTS / 256, BATCH);
  std_dist_kernel<<<g2, 256, 0, stream>>>(kappaWs, idxWs, partial);

  finalize_kernel<<<dim3(1), 64, 0, stream>>>(partial, out);
}